// Round 1
// baseline (136.746 us; speedup 1.0000x reference)
//
#include <hip/hip_runtime.h>
#include <hip/hip_bf16.h>

#define IN_F   4096
#define OUT_F  4096
#define QBLK   8
#define NBLKS  512
#define NTOK   1024
#define NCENT  2048

typedef unsigned int u32;
typedef unsigned short u16;
typedef __attribute__((ext_vector_type(8))) short short8;   // 8 bf16 (MFMA A/B frag)
typedef __attribute__((ext_vector_type(4))) float floatx4;  // MFMA C/D frag

// round-to-nearest-even fp32 -> bf16
__device__ __forceinline__ u16 f2bf(float f) {
  union { float f; u32 u; } v; v.f = f;
  u32 u = v.u;
  return (u16)((u + 0x7fffu + ((u >> 16) & 1u)) >> 16);
}

__device__ __forceinline__ void load_lds_16(const void* g, void* l) {
  __builtin_amdgcn_global_load_lds(
      (const __attribute__((address_space(1))) u32*)g,
      (__attribute__((address_space(3))) u32*)l, 16, 0, 0);
}

// ---------------------------------------------------------------------------
// cast fp32 -> bf16 (plain layout) -- used for centroids only
// ---------------------------------------------------------------------------
__global__ __launch_bounds__(256) void cast_bf16_kernel(
    const float* __restrict__ src, u16* __restrict__ dst) {
  int g = blockIdx.x * 256 + threadIdx.x;   // one 8-element chunk
  const float4* sv = (const float4*)src;
  float4 a = sv[(size_t)g * 2];
  float4 b = sv[(size_t)g * 2 + 1];
  union { u16 s[8]; uint4 v; } o;
  o.s[0] = f2bf(a.x); o.s[1] = f2bf(a.y); o.s[2] = f2bf(a.z); o.s[3] = f2bf(a.w);
  o.s[4] = f2bf(b.x); o.s[5] = f2bf(b.y); o.s[6] = f2bf(b.z); o.s[7] = f2bf(b.w);
  ((uint4*)dst)[g] = o.v;
}

// ---------------------------------------------------------------------------
// cast x fp32 -> bf16 in MFMA-fragment-ordered ("swizzled") layout:
//   elem (m,k) -> [(m>>4)*512 + (k>>3)]*128 + (m&15)*8 + (k&7)
// With this layout, a wave's A-fragment load (lane = quad*16+r16 reads
// A[m0+r16][k0+quad*8 .. +8]) is ONE contiguous 1 KB region -> perfectly
// coalesced global_load_dwordx4, no LDS staging needed in the GEMM.
// Block = (m-group of 16 rows) x (128 k elems = 16 quant blocks).
// Reads coalesced (16 lanes x 32 B contiguous); LDS bounce (XOR-swizzled to
// spread banks) makes the global writes fully coalesced too.
// ---------------------------------------------------------------------------
__global__ __launch_bounds__(256) void cast_swz_kernel(
    const float* __restrict__ src, u16* __restrict__ dst) {
  __shared__ __align__(16) u16 ls[256 * 8];      // 256 chunks of 16 B = 4 KB
  const int b = blockIdx.x;
  const int mg = b >> 5;          // m-group 0..63
  const int kq = b & 31;          // k-chunk of 128 elems, 0..31
  const int t = threadIdx.x;
  const int ml = t >> 4;          // m within group 0..15
  const int kbl = t & 15;         // quant block within chunk 0..15

  const float* p = src + (size_t)(mg * 16 + ml) * IN_F + kq * 128 + kbl * 8;
  float4 a = ((const float4*)p)[0];
  float4 c = ((const float4*)p)[1];
  union { u16 s[8]; uint4 v; } o;
  o.s[0] = f2bf(a.x); o.s[1] = f2bf(a.y); o.s[2] = f2bf(a.z); o.s[3] = f2bf(a.w);
  o.s[4] = f2bf(c.x); o.s[5] = f2bf(c.y); o.s[6] = f2bf(c.z); o.s[7] = f2bf(c.w);

  // store chunk (kbl, ml) at XOR-swizzled slot to avoid bank camping
  const int cidx = (kbl << 4) | (ml ^ kbl);
  *(uint4*)&ls[cidx * 8] = o.v;
  __syncthreads();

  // linear LDS read, un-swizzled global chunk position (still coalesced:
  // each 16-lane group covers one contiguous 256 B span, permuted within)
  const int g = (t & 0xF0) | ((t & 15) ^ ((t >> 4) & 15));
  uint4* dbase = (uint4*)(dst + (size_t)(mg * 512 + kq * 16) * 128);
  dbase[g] = ((const uint4*)ls)[t];
}

// ---------------------------------------------------------------------------
// Fused GEMM, barrier-free K-loop:
//   C[m][n] = sum_k x[m][k] * centroids[assign[(k/8)*OUT_F+n]][k%8]
// Block tile 128x128, 4 waves (2x2) each 64x64 (4x4 of mfma_f32_16x16x32_bf16).
// A fragments: direct coalesced global loads from the fragment-ordered xs
// (1 KB contiguous per instr), register double-buffered one iter ahead.
// B fragments: gathered from the 32 KB bf16 centroid table in LDS (read-only
// after a single startup barrier); assignment indices prefetched one iter
// ahead. NO __syncthreads in the main loop -> no vmcnt(0) drain stalls.
// Split-K over gridDim.z; s=0 -> d_out, s>0 -> partials.
// ---------------------------------------------------------------------------
__global__ __launch_bounds__(256, 3) void gemm_fused_kernel(
    const u16* __restrict__ xs,     // x bf16, fragment-ordered [64][512][16][8]
    const u16* __restrict__ centb,  // [NCENT][8] bf16
    const int* __restrict__ assign, // [NBLKS*OUT_F] block-major
    const float* __restrict__ bias,
    float* __restrict__ out0,       // d_out (chunk s=0)
    float* __restrict__ partials) { // (S-1) x [NTOK][OUT_F]
  __shared__ __align__(16) u16 cs[NCENT * 8];   // 32 KB centroid table (only LDS)

  const int t = threadIdx.x;
  const int lane = t & 63;
  const int wv = t >> 6;
  const int wm = wv >> 1;
  const int wn = wv & 1;
  const int quad = lane >> 4;
  const int r16 = lane & 15;
  const int m0 = blockIdx.y * 128;
  const int n0 = blockIdx.x * 128;
  const int s = blockIdx.z;
  const int kchunk = IN_F / gridDim.z;
  const int kb0 = (s * kchunk) >> 3;       // first quant block of this chunk
  const int iters = kchunk / 32;           // 4 quant blocks per iteration

  // stage centroid table: 2048 chunks of 16B = 8 per thread (DMA, no VGPR)
#pragma unroll
  for (int it = 0; it < 8; ++it) {
    int c = it * 256 + t;
    load_lds_16(centb + (size_t)c * 8, cs + (size_t)c * 8);
  }

  floatx4 acc[4][4];
#pragma unroll
  for (int i = 0; i < 4; ++i)
#pragma unroll
    for (int j = 0; j < 4; ++j)
#pragma unroll
      for (int r = 0; r < 4; ++r) acc[i][j][r] = 0.0f;

  const int ncol = n0 + wn * 64 + r16;
  const short8* xv = (const short8*)xs;
  const short8* csv = (const short8*)cs;

  // A-frag base indices (short8 units): ((m>>4)*512 + kb)*16 + (m&15)
  const int mgrp0 = (m0 >> 4) + wm * 4;
  size_t abase[4];
#pragma unroll
  for (int i = 0; i < 4; ++i)
    abase[i] = ((size_t)(mgrp0 + i) * 512 + kb0 + quad) * 16 + r16;

  const int* aptr = assign + (size_t)(kb0 + quad) * OUT_F + ncol;

  // prologue: load iter-0 A frags + indices
  short8 afc[4];
#pragma unroll
  for (int i = 0; i < 4; ++i) afc[i] = xv[abase[i]];
  int idxc[4];
#pragma unroll
  for (int j = 0; j < 4; ++j) idxc[j] = aptr[j * 16];

  __syncthreads();   // centroid table ready (single barrier of the kernel)

  for (int kt = 0; kt < iters; ++kt) {
    // prefetch next iteration's A frags + indices (uniform guard)
    short8 afn[4];
    int idxn[4];
    if (kt + 1 < iters) {
#pragma unroll
      for (int i = 0; i < 4; ++i) afn[i] = xv[abase[i] + (size_t)(kt + 1) * 64];
#pragma unroll
      for (int j = 0; j < 4; ++j) idxn[j] = aptr[(size_t)(kt + 1) * 4 * OUT_F + j * 16];
    }

    // gather B frags from LDS table (one 16 B lookup per lane per frag)
    short8 bfr[4];
#pragma unroll
    for (int j = 0; j < 4; ++j) bfr[j] = csv[idxc[j]];

    __builtin_amdgcn_s_setprio(1);
#pragma unroll
    for (int i = 0; i < 4; ++i)
#pragma unroll
      for (int j = 0; j < 4; ++j)
        acc[i][j] = __builtin_amdgcn_mfma_f32_16x16x32_bf16(afc[i], bfr[j], acc[i][j], 0, 0, 0);
    __builtin_amdgcn_s_setprio(0);

#pragma unroll
    for (int i = 0; i < 4; ++i) afc[i] = afn[i];
#pragma unroll
    for (int j = 0; j < 4; ++j) idxc[j] = idxn[j];
  }

  // epilogue: C/D layout col = lane&15 (+j*16), row = quad*4 + reg (+i*16)
  float* C = (s == 0) ? out0 : (partials + (size_t)(s - 1) * NTOK * OUT_F);
  const bool add_bias = (gridDim.z == 1);   // no reduce pass in S=1 fallback
  const int row_base = m0 + wm * 64 + quad * 4;
#pragma unroll
  for (int j = 0; j < 4; ++j) {
    const int col = ncol + j * 16;
    const float bv = add_bias ? bias[col] : 0.0f;
#pragma unroll
    for (int i = 0; i < 4; ++i) {
      const int row = row_base + i * 16;
#pragma unroll
      for (int r = 0; r < 4; ++r)
        C[(size_t)(row + r) * OUT_F + col] = acc[i][j][r] + bv;
    }
  }
}

// ---------------------------------------------------------------------------
// reduce: out += sum(partials) + bias   (float4 per thread)
// ---------------------------------------------------------------------------
__global__ __launch_bounds__(256) void reduce_kernel(
    float* __restrict__ out, const float* __restrict__ partials,
    const float* __restrict__ bias, int sm1) {
  int g = blockIdx.x * 256 + threadIdx.x;  // float4 index over [NTOK*OUT_F/4]
  float4 v = ((const float4*)out)[g];
  for (int s = 0; s < sm1; ++s) {
    float4 p = ((const float4*)(partials + (size_t)s * NTOK * OUT_F))[g];
    v.x += p.x; v.y += p.y; v.z += p.z; v.w += p.w;
  }
  float4 b = ((const float4*)bias)[g & (OUT_F / 4 - 1)];
  v.x += b.x; v.y += b.y; v.z += b.z; v.w += b.w;
  ((float4*)out)[g] = v;
}

extern "C" void kernel_launch(void* const* d_in, const int* in_sizes, int n_in,
                              void* d_out, int out_size, void* d_ws, size_t ws_size,
                              hipStream_t stream) {
  const float* x      = (const float*)d_in[0];  // [1024][4096] fp32
  const float* cent   = (const float*)d_in[1];  // [2048][8] fp32
  const float* bias   = (const float*)d_in[2];  // [4096] fp32
  const int*   assign = (const int*)d_in[3];    // [512*4096] int32
  float* out = (float*)d_out;

  // ws layout: xs (8 MB) | centb (32 KB) | partials (S-1)*16 MB
  const size_t xb_bytes   = (size_t)NTOK * IN_F * sizeof(u16);      // 8388608
  const size_t cent_bytes = (size_t)NCENT * 8 * sizeof(u16);        // 32768
  const size_t part_bytes = (size_t)NTOK * OUT_F * sizeof(float);   // 16777216
  u16*   xs       = (u16*)d_ws;
  u16*   centb    = (u16*)((char*)d_ws + xb_bytes);
  float* partials = (float*)((char*)d_ws + xb_bytes + cent_bytes);

  const size_t base = xb_bytes + cent_bytes;
  int S = 1;
  if (ws_size >= base + 3 * part_bytes) S = 4;
  else if (ws_size >= base + 1 * part_bytes) S = 2;

  hipLaunchKernelGGL(cast_swz_kernel, dim3(64 * 32), dim3(256), 0, stream, x, xs);
  hipLaunchKernelGGL(cast_bf16_kernel, dim3((NCENT * 8 / 8) / 256), dim3(256), 0, stream,
                     cent, centb);
  hipLaunchKernelGGL(gemm_fused_kernel, dim3(OUT_F / 128, NTOK / 128, S), dim3(256), 0, stream,
                     xs, centb, assign, bias, out, partials);
  if (S > 1)
    hipLaunchKernelGGL(reduce_kernel, dim3((NTOK * OUT_F / 4) / 256), dim3(256), 0, stream,
                       out, partials, bias, S - 1);
}